// Round 13
// baseline (375.026 us; speedup 1.0000x reference)
//
#include <hip/hip_runtime.h>
#include <math.h>

// Problem constants
#define HID 4096
#define NH  32
#define NKV 8
#define DH  128
#define SEQ 64
#define BS  16
#define MC  1024
#define QKV_N 6144                 // (NH + 2*NKV) * DH
#define NPAGES 64                  // MC / BS
#define KC  64                     // GEMM K-chunk (LDS tile depth)
#define KS  16                     // GEMM K-split factor
#define GQ  4                      // NH / NKV
#define CSPLIT 8                   // attention: 128-token chunks
#define TPS 128                    // tokens per split
#define NHQ (SEQ * NH)             // 2048 (s,qhead) pairs

// Static device scratch (BSS) — immune to ws_size.
__device__ float g_qkv[SEQ * QKV_N];            // 1.5 MB
__device__ float g_attn[SEQ * HID];             // 1.0 MB
__device__ float g_part[KS * SEQ * QKV_N];      // 25.2 MB (GEMM partials)
__device__ float g_po[CSPLIT * NHQ * DH];       // 8.4 MB (attn o-partials)
__device__ float g_pm[CSPLIT * NHQ];
__device__ float g_pl[CSPLIT * NHQ];

// ---------------------------------------------------------------------------
// Tiled GEMM with K-split (structure verified; KS now 16 for parallelism).
// ---------------------------------------------------------------------------
__global__ __launch_bounds__(256) void gemm_tile(const float* __restrict__ X,
                                                 const float* __restrict__ W,
                                                 float* __restrict__ P,
                                                 int N, int K) {
    __shared__ float Xs[KC][68];
    __shared__ float Ws[KC][68];
    const int tid = threadIdx.x;
    const int tx = tid & 15;
    const int ty = tid >> 4;
    const int jb = blockIdx.x * 64;
    const int ks = blockIdx.y;
    const int k_lo = ks * (K / KS);
    const int k_hi = k_lo + (K / KS);

    float4 a0 = {0,0,0,0}, a1 = {0,0,0,0}, a2 = {0,0,0,0}, a3 = {0,0,0,0};

    for (int k0 = k_lo; k0 < k_hi; k0 += KC) {
        #pragma unroll
        for (int r = 0; r < 4; ++r) {
            int idx = r * 256 + tid;
            int s  = idx >> 4;
            int k4 = idx & 15;
            float4 v = *(const float4*)(X + (size_t)s * K + k0 + k4 * 4);
            Xs[k4 * 4 + 0][s] = v.x;
            Xs[k4 * 4 + 1][s] = v.y;
            Xs[k4 * 4 + 2][s] = v.z;
            Xs[k4 * 4 + 3][s] = v.w;
        }
        #pragma unroll
        for (int r = 0; r < 4; ++r) {
            int idx = r * 256 + tid;
            int j  = idx >> 4;
            int k4 = idx & 15;
            float4 v = *(const float4*)(W + (size_t)(jb + j) * K + k0 + k4 * 4);
            Ws[k4 * 4 + 0][j] = v.x;
            Ws[k4 * 4 + 1][j] = v.y;
            Ws[k4 * 4 + 2][j] = v.z;
            Ws[k4 * 4 + 3][j] = v.w;
        }
        __syncthreads();
        #pragma unroll
        for (int kk = 0; kk < KC; ++kk) {
            float4 xv = *(const float4*)(&Xs[kk][ty * 4]);
            float4 wv = *(const float4*)(&Ws[kk][tx * 4]);
            a0.x = fmaf(xv.x, wv.x, a0.x); a0.y = fmaf(xv.x, wv.y, a0.y);
            a0.z = fmaf(xv.x, wv.z, a0.z); a0.w = fmaf(xv.x, wv.w, a0.w);
            a1.x = fmaf(xv.y, wv.x, a1.x); a1.y = fmaf(xv.y, wv.y, a1.y);
            a1.z = fmaf(xv.y, wv.z, a1.z); a1.w = fmaf(xv.y, wv.w, a1.w);
            a2.x = fmaf(xv.z, wv.x, a2.x); a2.y = fmaf(xv.z, wv.y, a2.y);
            a2.z = fmaf(xv.z, wv.z, a2.z); a2.w = fmaf(xv.z, wv.w, a2.w);
            a3.x = fmaf(xv.w, wv.x, a3.x); a3.y = fmaf(xv.w, wv.y, a3.y);
            a3.z = fmaf(xv.w, wv.z, a3.z); a3.w = fmaf(xv.w, wv.w, a3.w);
        }
        __syncthreads();
    }
    float* pb = P + (size_t)ks * SEQ * N;
    *(float4*)(pb + (size_t)(ty * 4 + 0) * N + jb + tx * 4) = a0;
    *(float4*)(pb + (size_t)(ty * 4 + 1) * N + jb + tx * 4) = a1;
    *(float4*)(pb + (size_t)(ty * 4 + 2) * N + jb + tx * 4) = a2;
    *(float4*)(pb + (size_t)(ty * 4 + 3) * N + jb + tx * 4) = a3;
}

// reduce over KS=16 partials
__global__ __launch_bounds__(256) void reduce_ks(const float* __restrict__ P,
                                                 float* __restrict__ Y, int n4) {
    int t = blockIdx.x * 256 + threadIdx.x;
    if (t >= n4) return;
    const float4* p4 = (const float4*)P;
    float4 r = p4[t];
    #pragma unroll
    for (int i = 1; i < KS; ++i) {
        float4 v = p4[t + (size_t)i * n4];
        r.x += v.x; r.y += v.y; r.z += v.z; r.w += v.w;
    }
    ((float4*)Y)[t] = r;
}

// ---------------------------------------------------------------------------
// Scalar RoPE (unchanged, verified). sincosf(x, &sin, &cos) — sin FIRST.
// ---------------------------------------------------------------------------
__global__ __launch_bounds__(256) void rope_scalar(float* __restrict__ qkv,
                                                   const int* __restrict__ ia,
                                                   const int* __restrict__ ib) {
    int t = blockIdx.x * 256 + threadIdx.x;
    if (t >= SEQ * (NH + NKV) * 64) return;
    int i = t & 63;
    int h = (t >> 6) % (NH + NKV);
    int s = t / ((NH + NKV) * 64);
    int pos = max(ia[s], ib[s]) - 1;
    float* base = qkv + (size_t)s * QKV_N + (size_t)h * DH;
    float ang = (float)pos / powf(10000.0f, (float)i * 2.0f / (float)DH);
    float sn, c;
    sincosf(ang, &sn, &c);
    float x1 = base[i];
    float x2 = base[i + 64];
    base[i]      = x1 * c - x2 * sn;
    base[i + 64] = x2 * c + x1 * sn;
}

// ---------------------------------------------------------------------------
// Flash-decode attention pass 1, v4: register-resident, one barrier per block.
// Block per (s, kv, split); 4 waves = 4 q heads; TPS=128 (lane owns tokens
// c_lo+lane and c_lo+64+lane). Scores and probs in registers; softmax via
// shfl; PV reads V direct-to-register 16 rows deep, p broadcast via shfl.
// Invalid tokens (>= L) get p=0 and load harmless in-bounds garbage.
// ---------------------------------------------------------------------------
__global__ __launch_bounds__(256) void attn_split(const float* __restrict__ qkv,
                                                  const float* __restrict__ k_cache,
                                                  const float* __restrict__ v_cache,
                                                  const int* __restrict__ ia,
                                                  const int* __restrict__ ib,
                                                  const int* __restrict__ block_tables,
                                                  float* __restrict__ po,
                                                  float* __restrict__ pm,
                                                  float* __restrict__ pl) {
    __shared__ float qs[GQ][DH];     // 2 KB
    __shared__ int   btl[NPAGES];    // 256 B

    int b  = blockIdx.x;
    int t  = b & 7;                 // split
    int kv = (b >> 3) & 7;
    int s  = b >> 6;
    int tid = threadIdx.x;
    int lane = tid & 63;
    int g = tid >> 6;

    int L   = max(ia[s], ib[s]);
    int pos = L - 1;
    int c_lo = t * TPS;
    if (c_lo >= L) return;          // inactive split: no writes (combine skips)
    int n = min(TPS, L - c_lo);

    if (tid < NPAGES) btl[tid] = block_tables[s * NPAGES + tid];
    for (int i = tid; i < GQ * DH; i += 256)
        qs[i >> 7][i & 127] = qkv[(size_t)s * QKV_N + (size_t)(kv * GQ) * DH + i]
                              * 0.08838834764831845f;
    __syncthreads();

    const float* knew = qkv + (size_t)s * QKV_N + (size_t)NH * DH + (size_t)kv * DH;
    const float* vnew = qkv + (size_t)s * QKV_N + (size_t)(NH + NKV) * DH + (size_t)kv * DH;
    const float4* q4 = (const float4*)qs[g];

    // Phase 1: two K-row dots per lane (tokens c0, c1), 64 loads in flight.
    int c0 = c_lo + lane;
    int c1 = c0 + 64;
    const float* kr0 = (c0 == pos)
        ? knew
        : k_cache + ((size_t)btl[c0 >> 4] * BS + (c0 & 15)) * (size_t)(NKV * DH)
                  + (size_t)kv * DH;
    const float* kr1 = (c1 == pos)
        ? knew
        : k_cache + ((size_t)btl[c1 >> 4] * BS + (c1 & 15)) * (size_t)(NKV * DH)
                  + (size_t)kv * DH;
    const float4* k40 = (const float4*)kr0;
    const float4* k41 = (const float4*)kr1;
    float dA = 0.f, dB = 0.f, dC = 0.f, dD = 0.f;
    #pragma unroll
    for (int i = 0; i < 32; i += 2) {
        float4 q0 = q4[i], q1 = q4[i + 1];
        float4 a0 = k40[i], a1 = k40[i + 1];
        float4 b0 = k41[i], b1 = k41[i + 1];
        dA += q0.x * a0.x + q0.y * a0.y + q0.z * a0.z + q0.w * a0.w;
        dC += q1.x * a1.x + q1.y * a1.y + q1.z * a1.z + q1.w * a1.w;
        dB += q0.x * b0.x + q0.y * b0.y + q0.z * b0.z + q0.w * b0.w;
        dD += q1.x * b1.x + q1.y * b1.y + q1.z * b1.z + q1.w * b1.w;
    }
    float scL = (c0 < L) ? (dA + dC) : -1e30f;
    float scH = (c1 < L) ? (dB + dD) : -1e30f;

    // Phase 2: wave softmax, all in registers.
    float m = fmaxf(scL, scH);
    #pragma unroll
    for (int off = 32; off; off >>= 1) m = fmaxf(m, __shfl_xor(m, off, 64));
    float pL = (c0 < L) ? expf(scL - m) : 0.f;
    float pH = (c1 < L) ? expf(scH - m) : 0.f;
    float l = pL + pH;
    #pragma unroll
    for (int off = 32; off; off >>= 1) l += __shfl_xor(l, off, 64);

    // Phase 3: PV direct-to-register, 16 V rows in flight; lane owns dims 2l,2l+1.
    float o0 = 0.f, o1 = 0.f;
    #pragma unroll
    for (int b8 = 0; b8 < 8; ++b8) {
        int base = b8 * 16;
        if (base >= n) break;       // block-uniform
        float2 vv[16];
        #pragma unroll
        for (int j = 0; j < 16; ++j) {
            int c = c_lo + base + j;
            const float* vr = (c == pos)
                ? vnew
                : v_cache + ((size_t)btl[c >> 4] * BS + (c & 15)) * (size_t)(NKV * DH)
                          + (size_t)kv * DH;
            vv[j] = ((const float2*)vr)[lane];
        }
        #pragma unroll
        for (int j = 0; j < 16; ++j) {
            float pv = __shfl((b8 < 4) ? pL : pH, (base & 63) + j, 64);
            o0 = fmaf(pv, vv[j].x, o0);
            o1 = fmaf(pv, vv[j].y, o1);
        }
    }

    int idx = t * NHQ + s * NH + kv * GQ + g;
    float* ob = po + (size_t)idx * DH;
    ((float2*)ob)[lane] = make_float2(o0, o1);
    if (lane == 0) {
        pm[idx] = m;
        pl[idx] = l;
    }
}

// ---------------------------------------------------------------------------
// Combine: block per (s,qh); derives active split count from L (no sentinel
// reads of poisoned memory).
// ---------------------------------------------------------------------------
__global__ __launch_bounds__(128) void attn_combine(const float* __restrict__ po,
                                                    const float* __restrict__ pm,
                                                    const float* __restrict__ pl,
                                                    const int* __restrict__ ia,
                                                    const int* __restrict__ ib,
                                                    float* __restrict__ attn_out) {
    int sh = blockIdx.x;
    int s  = sh >> 5;
    int d  = threadIdx.x;
    int L  = max(ia[s], ib[s]);
    int nact = (L + TPS - 1) / TPS;   // 1..8
    float mv[CSPLIT];
    float M = -1e30f;
    for (int i = 0; i < nact; ++i) {
        mv[i] = pm[i * NHQ + sh];
        M = fmaxf(M, mv[i]);
    }
    float num = 0.f, denom = 0.f;
    for (int i = 0; i < nact; ++i) {
        float w = expf(mv[i] - M);
        denom += pl[i * NHQ + sh] * w;
        num   += po[(size_t)(i * NHQ + sh) * DH + d] * w;
    }
    attn_out[(size_t)sh * DH + d] = num / denom;
}

// ---------------------------------------------------------------------------
extern "C" void kernel_launch(void* const* d_in, const int* in_sizes, int n_in,
                              void* d_out, int out_size, void* d_ws, size_t ws_size,
                              hipStream_t stream) {
    const float *hidden = nullptr, *k_cache = nullptr, *v_cache = nullptr;
    const float *qkv_w = nullptr, *o_w = nullptr;
    const int *i64a = nullptr, *i64b = nullptr, *block_tables = nullptr;
    for (int i = 0; i < n_in; ++i) {
        switch (in_sizes[i]) {
            case SEQ * HID:          hidden = (const float*)d_in[i]; break;
            case 4096 * BS * NKV * DH:
                if (!k_cache) k_cache = (const float*)d_in[i];
                else          v_cache = (const float*)d_in[i];
                break;
            case QKV_N * HID:        qkv_w = (const float*)d_in[i]; break;
            case HID * HID:          o_w   = (const float*)d_in[i]; break;
            case SEQ * NPAGES:       block_tables = (const int*)d_in[i]; break;
            case SEQ:
                if (!i64a) i64a = (const int*)d_in[i];
                else       i64b = (const int*)d_in[i];
                break;
        }
    }
    float* out = (float*)d_out;

    static float* qkv_p  = nullptr;
    static float* attn_p = nullptr;
    static float* part_p = nullptr;
    static float* po_p   = nullptr;
    static float* pm_p   = nullptr;
    static float* pl_p   = nullptr;
    if (!qkv_p) {
        void* p;
        hipGetSymbolAddress(&p, HIP_SYMBOL(g_qkv));  qkv_p  = (float*)p;
        hipGetSymbolAddress(&p, HIP_SYMBOL(g_attn)); attn_p = (float*)p;
        hipGetSymbolAddress(&p, HIP_SYMBOL(g_part)); part_p = (float*)p;
        hipGetSymbolAddress(&p, HIP_SYMBOL(g_po));   po_p   = (float*)p;
        hipGetSymbolAddress(&p, HIP_SYMBOL(g_pm));   pm_p   = (float*)p;
        hipGetSymbolAddress(&p, HIP_SYMBOL(g_pl));   pl_p   = (float*)p;
    }

    // 1) QKV projection
    gemm_tile<<<dim3(QKV_N / 64, KS), 256, 0, stream>>>(hidden, qkv_w, part_p,
                                                        QKV_N, HID);
    reduce_ks<<<(SEQ * QKV_N / 4 + 255) / 256, 256, 0, stream>>>(part_p, qkv_p,
                                                                 SEQ * QKV_N / 4);
    // 2) RoPE
    rope_scalar<<<(SEQ * (NH + NKV) * 64) / 256, 256, 0, stream>>>(qkv_p, i64a, i64b);
    // 3) Flash-decode attention (128-token chunks, register-resident)
    attn_split<<<SEQ * NKV * CSPLIT, 256, 0, stream>>>(qkv_p, k_cache, v_cache,
                                                       i64a, i64b, block_tables,
                                                       po_p, pm_p, pl_p);
    attn_combine<<<NHQ, 128, 0, stream>>>(po_p, pm_p, pl_p, i64a, i64b, attn_p);
    // 4) Output projection
    gemm_tile<<<dim3(HID / 64, KS), 256, 0, stream>>>(attn_p, o_w, part_p,
                                                      HID, HID);
    reduce_ks<<<(SEQ * HID / 4 + 255) / 256, 256, 0, stream>>>(part_p, out,
                                                               SEQ * HID / 4);
}

// Round 14
// 235.228 us; speedup vs baseline: 1.5943x; 1.5943x over previous
//
#include <hip/hip_runtime.h>
#include <math.h>

// Problem constants
#define HID 4096
#define NH  32
#define NKV 8
#define DH  128
#define SEQ 64
#define BS  16
#define MC  1024
#define QKV_N 6144                 // (NH + 2*NKV) * DH
#define NPAGES 64                  // MC / BS
#define KC  64                     // GEMM K-chunk (LDS tile depth)
#define KS  16                     // GEMM K-split factor
#define GQ  4                      // NH / NKV
#define CSPLIT 8                   // attention: 128-token chunks
#define TPS 128                    // tokens per split
#define RT  32                     // tokens per round
#define NHQ (SEQ * NH)             // 2048 (s,qhead) pairs

// Static device scratch (BSS) — immune to ws_size.
__device__ float g_qkv[SEQ * QKV_N];            // 1.5 MB
__device__ float g_attn[SEQ * HID];             // 1.0 MB
__device__ float g_part[KS * SEQ * QKV_N];      // 25.2 MB (GEMM partials)
__device__ float g_po[CSPLIT * NHQ * DH];       // 8.4 MB (attn o-partials)
__device__ float g_pm[CSPLIT * NHQ];
__device__ float g_pl[CSPLIT * NHQ];

// ---------------------------------------------------------------------------
// Tiled GEMM with K-split (unchanged from R13).
// ---------------------------------------------------------------------------
__global__ __launch_bounds__(256) void gemm_tile(const float* __restrict__ X,
                                                 const float* __restrict__ W,
                                                 float* __restrict__ P,
                                                 int N, int K) {
    __shared__ float Xs[KC][68];
    __shared__ float Ws[KC][68];
    const int tid = threadIdx.x;
    const int tx = tid & 15;
    const int ty = tid >> 4;
    const int jb = blockIdx.x * 64;
    const int ks = blockIdx.y;
    const int k_lo = ks * (K / KS);
    const int k_hi = k_lo + (K / KS);

    float4 a0 = {0,0,0,0}, a1 = {0,0,0,0}, a2 = {0,0,0,0}, a3 = {0,0,0,0};

    for (int k0 = k_lo; k0 < k_hi; k0 += KC) {
        #pragma unroll
        for (int r = 0; r < 4; ++r) {
            int idx = r * 256 + tid;
            int s  = idx >> 4;
            int k4 = idx & 15;
            float4 v = *(const float4*)(X + (size_t)s * K + k0 + k4 * 4);
            Xs[k4 * 4 + 0][s] = v.x;
            Xs[k4 * 4 + 1][s] = v.y;
            Xs[k4 * 4 + 2][s] = v.z;
            Xs[k4 * 4 + 3][s] = v.w;
        }
        #pragma unroll
        for (int r = 0; r < 4; ++r) {
            int idx = r * 256 + tid;
            int j  = idx >> 4;
            int k4 = idx & 15;
            float4 v = *(const float4*)(W + (size_t)(jb + j) * K + k0 + k4 * 4);
            Ws[k4 * 4 + 0][j] = v.x;
            Ws[k4 * 4 + 1][j] = v.y;
            Ws[k4 * 4 + 2][j] = v.z;
            Ws[k4 * 4 + 3][j] = v.w;
        }
        __syncthreads();
        #pragma unroll
        for (int kk = 0; kk < KC; ++kk) {
            float4 xv = *(const float4*)(&Xs[kk][ty * 4]);
            float4 wv = *(const float4*)(&Ws[kk][tx * 4]);
            a0.x = fmaf(xv.x, wv.x, a0.x); a0.y = fmaf(xv.x, wv.y, a0.y);
            a0.z = fmaf(xv.x, wv.z, a0.z); a0.w = fmaf(xv.x, wv.w, a0.w);
            a1.x = fmaf(xv.y, wv.x, a1.x); a1.y = fmaf(xv.y, wv.y, a1.y);
            a1.z = fmaf(xv.y, wv.z, a1.z); a1.w = fmaf(xv.y, wv.w, a1.w);
            a2.x = fmaf(xv.z, wv.x, a2.x); a2.y = fmaf(xv.z, wv.y, a2.y);
            a2.z = fmaf(xv.z, wv.z, a2.z); a2.w = fmaf(xv.z, wv.w, a2.w);
            a3.x = fmaf(xv.w, wv.x, a3.x); a3.y = fmaf(xv.w, wv.y, a3.y);
            a3.z = fmaf(xv.w, wv.z, a3.z); a3.w = fmaf(xv.w, wv.w, a3.w);
        }
        __syncthreads();
    }
    float* pb = P + (size_t)ks * SEQ * N;
    *(float4*)(pb + (size_t)(ty * 4 + 0) * N + jb + tx * 4) = a0;
    *(float4*)(pb + (size_t)(ty * 4 + 1) * N + jb + tx * 4) = a1;
    *(float4*)(pb + (size_t)(ty * 4 + 2) * N + jb + tx * 4) = a2;
    *(float4*)(pb + (size_t)(ty * 4 + 3) * N + jb + tx * 4) = a3;
}

__global__ __launch_bounds__(256) void reduce_ks(const float* __restrict__ P,
                                                 float* __restrict__ Y, int n4) {
    int t = blockIdx.x * 256 + threadIdx.x;
    if (t >= n4) return;
    const float4* p4 = (const float4*)P;
    float4 r = p4[t];
    #pragma unroll
    for (int i = 1; i < KS; ++i) {
        float4 v = p4[t + (size_t)i * n4];
        r.x += v.x; r.y += v.y; r.z += v.z; r.w += v.w;
    }
    ((float4*)Y)[t] = r;
}

// ---------------------------------------------------------------------------
// Scalar RoPE (unchanged, verified). sincosf(x, &sin, &cos) — sin FIRST.
// ---------------------------------------------------------------------------
__global__ __launch_bounds__(256) void rope_scalar(float* __restrict__ qkv,
                                                   const int* __restrict__ ia,
                                                   const int* __restrict__ ib) {
    int t = blockIdx.x * 256 + threadIdx.x;
    if (t >= SEQ * (NH + NKV) * 64) return;
    int i = t & 63;
    int h = (t >> 6) % (NH + NKV);
    int s = t / ((NH + NKV) * 64);
    int pos = max(ia[s], ib[s]) - 1;
    float* base = qkv + (size_t)s * QKV_N + (size_t)h * DH;
    float ang = (float)pos / powf(10000.0f, (float)i * 2.0f / (float)DH);
    float sn, c;
    sincosf(ang, &sn, &c);
    float x1 = base[i];
    float x2 = base[i + 64];
    base[i]      = x1 * c - x2 * sn;
    base[i + 64] = x2 * c + x1 * sn;
}

// ---------------------------------------------------------------------------
// Flash-decode attention v5: page-staged LDS, double-buffered, 1 barrier/round.
// Block per (s, kv, split); 4 waves = 4 q heads; rounds of 32 tokens.
// Staging: coalesced (8 threads x float4 per 512B row) into named registers,
// then LDS. Phase1 lane=(token,half) dot from LDS + shfl combine. Online
// softmax in registers. PV from LDS with p broadcast via shfl.
// ---------------------------------------------------------------------------
__global__ __launch_bounds__(256) void attn_page(const float* __restrict__ qkv,
                                                 const float* __restrict__ k_cache,
                                                 const float* __restrict__ v_cache,
                                                 const int* __restrict__ ia,
                                                 const int* __restrict__ ib,
                                                 const int* __restrict__ block_tables,
                                                 float* __restrict__ po,
                                                 float* __restrict__ pm,
                                                 float* __restrict__ pl) {
    __shared__ float Klds[2][RT][129];   // 33.0 KB (pad 129: 2-way only)
    __shared__ float Vlds[2][RT][130];   // 33.3 KB (pad 130: float2-aligned, 2-way)
    __shared__ float qs[GQ][DH];         // 2 KB
    __shared__ int   btl[NPAGES];        // 256 B

    int b  = blockIdx.x;
    int t  = b & 7;
    int kv = (b >> 3) & 7;
    int s  = b >> 6;
    int tid = threadIdx.x;
    int lane = tid & 63;
    int g = tid >> 6;

    int L   = max(ia[s], ib[s]);
    int pos = L - 1;
    int c_lo = t * TPS;
    if (c_lo >= L) return;              // inactive split (block-uniform)
    int n = min(TPS, L - c_lo);
    int nrounds = (n + RT - 1) >> 5;

    if (tid < NPAGES) btl[tid] = block_tables[s * NPAGES + tid];
    for (int i = tid; i < GQ * DH; i += 256)
        qs[i >> 7][i & 127] = qkv[(size_t)s * QKV_N + (size_t)(kv * GQ) * DH + i]
                              * 0.08838834764831845f;
    __syncthreads();

    const float* knew = qkv + (size_t)s * QKV_N + (size_t)NH * DH + (size_t)kv * DH;
    const float* vnew = qkv + (size_t)s * QKV_N + (size_t)(NH + NKV) * DH + (size_t)kv * DH;

    // staging role: row sr (0..31), float4-slot sq (0..7) -> slots sq, sq+8, sq+16, sq+24
    const int sr = tid >> 3;
    const int sq = tid & 7;

    float4 ka0, ka1, ka2, ka3, va0, va1, va2, va3;

#define LOADR(BASE) do {                                                        \
    int cc = c_lo + (BASE) + sr;                                                \
    const float* kp_ = (cc == pos) ? knew                                       \
        : k_cache + ((size_t)btl[cc >> 4] * BS + (cc & 15)) * (size_t)(NKV * DH)\
                  + (size_t)kv * DH;                                            \
    const float* vp_ = (cc == pos) ? vnew                                       \
        : v_cache + ((size_t)btl[cc >> 4] * BS + (cc & 15)) * (size_t)(NKV * DH)\
                  + (size_t)kv * DH;                                            \
    const float4* kp4_ = (const float4*)kp_;                                    \
    const float4* vp4_ = (const float4*)vp_;                                    \
    ka0 = kp4_[sq];      ka1 = kp4_[sq + 8];                                    \
    ka2 = kp4_[sq + 16]; ka3 = kp4_[sq + 24];                                   \
    va0 = vp4_[sq];      va1 = vp4_[sq + 8];                                    \
    va2 = vp4_[sq + 16]; va3 = vp4_[sq + 24];                                   \
} while (0)

#define WRITER(BUF) do {                                                        \
    float* kd_ = &Klds[BUF][sr][0];                                             \
    kd_[4*sq+0]=ka0.x; kd_[4*sq+1]=ka0.y; kd_[4*sq+2]=ka0.z; kd_[4*sq+3]=ka0.w; \
    kd_[4*(sq+8)+0]=ka1.x; kd_[4*(sq+8)+1]=ka1.y;                               \
    kd_[4*(sq+8)+2]=ka1.z; kd_[4*(sq+8)+3]=ka1.w;                               \
    kd_[4*(sq+16)+0]=ka2.x; kd_[4*(sq+16)+1]=ka2.y;                             \
    kd_[4*(sq+16)+2]=ka2.z; kd_[4*(sq+16)+3]=ka2.w;                             \
    kd_[4*(sq+24)+0]=ka3.x; kd_[4*(sq+24)+1]=ka3.y;                             \
    kd_[4*(sq+24)+2]=ka3.z; kd_[4*(sq+24)+3]=ka3.w;                             \
    float* vd_ = &Vlds[BUF][sr][0];                                             \
    *(float2*)&vd_[4*sq+0]      = make_float2(va0.x, va0.y);                    \
    *(float2*)&vd_[4*sq+2]      = make_float2(va0.z, va0.w);                    \
    *(float2*)&vd_[4*(sq+8)+0]  = make_float2(va1.x, va1.y);                    \
    *(float2*)&vd_[4*(sq+8)+2]  = make_float2(va1.z, va1.w);                    \
    *(float2*)&vd_[4*(sq+16)+0] = make_float2(va2.x, va2.y);                    \
    *(float2*)&vd_[4*(sq+16)+2] = make_float2(va2.z, va2.w);                    \
    *(float2*)&vd_[4*(sq+24)+0] = make_float2(va3.x, va3.y);                    \
    *(float2*)&vd_[4*(sq+24)+2] = make_float2(va3.z, va3.w);                    \
} while (0)

    // prologue: stage round 0
    LOADR(0);
    WRITER(0);
    __syncthreads();

    float m = -1e30f, l = 0.f, o0 = 0.f, o1 = 0.f;
    int cur = 0;
    const int tkn = lane & 31;          // token within round
    const int hh  = lane >> 5;          // which half of the 128-dim dot

    for (int r = 0; r < nrounds; ++r) {
        int base = r << 5;
        if (r + 1 < nrounds) LOADR(base + RT);   // issue next-round loads (no wait)

        // Phase 1: 64-float half-dot per lane from LDS, combine halves via shfl.
        const float* krow = &Klds[cur][tkn][hh * 64];
        const float* qrow = &qs[g][hh * 64];
        float acc = 0.f;
        #pragma unroll
        for (int i = 0; i < 64; ++i) acc = fmaf(qrow[i], krow[i], acc);
        acc += __shfl_xor(acc, 32, 64);
        int c = c_lo + base + tkn;
        float scv = (c < L) ? acc : -1e30f;

        // round max over 32 tokens (butterfly over token bits; both halves equal)
        float rm = scv;
        #pragma unroll
        for (int off = 16; off; off >>= 1) rm = fmaxf(rm, __shfl_xor(rm, off, 64));
        float m_new = fmaxf(m, rm);
        float p = (c < L) ? expf(scv - m_new) : 0.f;
        float ps = p;
        #pragma unroll
        for (int off = 16; off; off >>= 1) ps += __shfl_xor(ps, off, 64);
        float rescale = expf(m - m_new);
        l = l * rescale + ps;
        o0 *= rescale; o1 *= rescale;
        m = m_new;

        // PV: 32 tokens from LDS; p broadcast from lane j (token j, half 0).
        int cnt = min(RT, n - base);
        for (int j = 0; j < cnt; ++j) {
            float pj = __shfl(p, j, 64);
            float2 v = *(const float2*)(&Vlds[cur][j][2 * lane]);
            o0 = fmaf(pj, v.x, o0);
            o1 = fmaf(pj, v.y, o1);
        }

        if (r + 1 < nrounds) {
            WRITER(cur ^ 1);            // vmcnt wait folded here by compiler
            __syncthreads();
            cur ^= 1;
        }
    }

    int idx = t * NHQ + s * NH + kv * GQ + g;
    float* ob = po + (size_t)idx * DH;
    ((float2*)ob)[lane] = make_float2(o0, o1);
    if (lane == 0) {
        pm[idx] = m;
        pl[idx] = l;
    }
#undef LOADR
#undef WRITER
}

// ---------------------------------------------------------------------------
// Combine: block per (s,qh); active split count derived from L.
// ---------------------------------------------------------------------------
__global__ __launch_bounds__(128) void attn_combine(const float* __restrict__ po,
                                                    const float* __restrict__ pm,
                                                    const float* __restrict__ pl,
                                                    const int* __restrict__ ia,
                                                    const int* __restrict__ ib,
                                                    float* __restrict__ attn_out) {
    int sh = blockIdx.x;
    int s  = sh >> 5;
    int d  = threadIdx.x;
    int L  = max(ia[s], ib[s]);
    int nact = (L + TPS - 1) / TPS;   // 1..8
    float mv[CSPLIT];
    float M = -1e30f;
    for (int i = 0; i < nact; ++i) {
        mv[i] = pm[i * NHQ + sh];
        M = fmaxf(M, mv[i]);
    }
    float num = 0.f, denom = 0.f;
    for (int i = 0; i < nact; ++i) {
        float w = expf(mv[i] - M);
        denom += pl[i * NHQ + sh] * w;
        num   += po[(size_t)(i * NHQ + sh) * DH + d] * w;
    }
    attn_out[(size_t)sh * DH + d] = num / denom;
}

// ---------------------------------------------------------------------------
extern "C" void kernel_launch(void* const* d_in, const int* in_sizes, int n_in,
                              void* d_out, int out_size, void* d_ws, size_t ws_size,
                              hipStream_t stream) {
    const float *hidden = nullptr, *k_cache = nullptr, *v_cache = nullptr;
    const float *qkv_w = nullptr, *o_w = nullptr;
    const int *i64a = nullptr, *i64b = nullptr, *block_tables = nullptr;
    for (int i = 0; i < n_in; ++i) {
        switch (in_sizes[i]) {
            case SEQ * HID:          hidden = (const float*)d_in[i]; break;
            case 4096 * BS * NKV * DH:
                if (!k_cache) k_cache = (const float*)d_in[i];
                else          v_cache = (const float*)d_in[i];
                break;
            case QKV_N * HID:        qkv_w = (const float*)d_in[i]; break;
            case HID * HID:          o_w   = (const float*)d_in[i]; break;
            case SEQ * NPAGES:       block_tables = (const int*)d_in[i]; break;
            case SEQ:
                if (!i64a) i64a = (const int*)d_in[i];
                else       i64b = (const int*)d_in[i];
                break;
        }
    }
    float* out = (float*)d_out;

    static float* qkv_p  = nullptr;
    static float* attn_p = nullptr;
    static float* part_p = nullptr;
    static float* po_p   = nullptr;
    static float* pm_p   = nullptr;
    static float* pl_p   = nullptr;
    if (!qkv_p) {
        void* p;
        hipGetSymbolAddress(&p, HIP_SYMBOL(g_qkv));  qkv_p  = (float*)p;
        hipGetSymbolAddress(&p, HIP_SYMBOL(g_attn)); attn_p = (float*)p;
        hipGetSymbolAddress(&p, HIP_SYMBOL(g_part)); part_p = (float*)p;
        hipGetSymbolAddress(&p, HIP_SYMBOL(g_po));   po_p   = (float*)p;
        hipGetSymbolAddress(&p, HIP_SYMBOL(g_pm));   pm_p   = (float*)p;
        hipGetSymbolAddress(&p, HIP_SYMBOL(g_pl));   pl_p   = (float*)p;
    }

    // 1) QKV projection
    gemm_tile<<<dim3(QKV_N / 64, KS), 256, 0, stream>>>(hidden, qkv_w, part_p,
                                                        QKV_N, HID);
    reduce_ks<<<(SEQ * QKV_N / 4 + 255) / 256, 256, 0, stream>>>(part_p, qkv_p,
                                                                 SEQ * QKV_N / 4);
    // 2) RoPE
    rope_scalar<<<(SEQ * (NH + NKV) * 64) / 256, 256, 0, stream>>>(qkv_p, i64a, i64b);
    // 3) Flash-decode attention (page-staged, double-buffered)
    attn_page<<<SEQ * NKV * CSPLIT, 256, 0, stream>>>(qkv_p, k_cache, v_cache,
                                                      i64a, i64b, block_tables,
                                                      po_p, pm_p, pl_p);
    attn_combine<<<NHQ, 128, 0, stream>>>(po_p, pm_p, pl_p, i64a, i64b, attn_p);
    // 4) Output projection
    gemm_tile<<<dim3(HID / 64, KS), 256, 0, stream>>>(attn_p, o_w, part_p,
                                                      HID, HID);
    reduce_ks<<<(SEQ * HID / 4 + 255) / 256, 256, 0, stream>>>(part_p, out,
                                                               SEQ * HID / 4);
}

// Round 15
// 206.571 us; speedup vs baseline: 1.8155x; 1.1387x over previous
//
#include <hip/hip_runtime.h>
#include <math.h>

// Problem constants
#define HID 4096
#define NH  32
#define NKV 8
#define DH  128
#define SEQ 64
#define BS  16
#define MC  1024
#define QKV_N 6144                 // (NH + 2*NKV) * DH
#define NPAGES 64                  // MC / BS
#define KC  64                     // GEMM K-chunk (LDS tile depth)
#define KS  16                     // GEMM K-split factor
#define GQ  4                      // NH / NKV
#define CSPLIT 8                   // attention: 128-token chunks
#define TPS 128                    // tokens per split
#define RT  32                     // tokens per round
#define NHQ (SEQ * NH)             // 2048 (s,qhead) pairs
#define SCALE 0.08838834764831845f

// Static device scratch (BSS) — immune to ws_size.
__device__ float g_qkv[SEQ * QKV_N];
__device__ float g_attn[SEQ * HID];
__device__ float g_part[KS * SEQ * QKV_N];      // GEMM partials
__device__ float g_po[CSPLIT * NHQ * DH];       // attn o-partials
__device__ float g_pm[CSPLIT * NHQ];
__device__ float g_pl[CSPLIT * NHQ];

// ---------------------------------------------------------------------------
// Tiled GEMM with K-split (unchanged, verified).
// ---------------------------------------------------------------------------
__global__ __launch_bounds__(256) void gemm_tile(const float* __restrict__ X,
                                                 const float* __restrict__ W,
                                                 float* __restrict__ P,
                                                 int N, int K) {
    __shared__ float Xs[KC][68];
    __shared__ float Ws[KC][68];
    const int tid = threadIdx.x;
    const int tx = tid & 15;
    const int ty = tid >> 4;
    const int jb = blockIdx.x * 64;
    const int ks = blockIdx.y;
    const int k_lo = ks * (K / KS);
    const int k_hi = k_lo + (K / KS);

    float4 a0 = {0,0,0,0}, a1 = {0,0,0,0}, a2 = {0,0,0,0}, a3 = {0,0,0,0};

    for (int k0 = k_lo; k0 < k_hi; k0 += KC) {
        #pragma unroll
        for (int r = 0; r < 4; ++r) {
            int idx = r * 256 + tid;
            int s  = idx >> 4;
            int k4 = idx & 15;
            float4 v = *(const float4*)(X + (size_t)s * K + k0 + k4 * 4);
            Xs[k4 * 4 + 0][s] = v.x;
            Xs[k4 * 4 + 1][s] = v.y;
            Xs[k4 * 4 + 2][s] = v.z;
            Xs[k4 * 4 + 3][s] = v.w;
        }
        #pragma unroll
        for (int r = 0; r < 4; ++r) {
            int idx = r * 256 + tid;
            int j  = idx >> 4;
            int k4 = idx & 15;
            float4 v = *(const float4*)(W + (size_t)(jb + j) * K + k0 + k4 * 4);
            Ws[k4 * 4 + 0][j] = v.x;
            Ws[k4 * 4 + 1][j] = v.y;
            Ws[k4 * 4 + 2][j] = v.z;
            Ws[k4 * 4 + 3][j] = v.w;
        }
        __syncthreads();
        #pragma unroll
        for (int kk = 0; kk < KC; ++kk) {
            float4 xv = *(const float4*)(&Xs[kk][ty * 4]);
            float4 wv = *(const float4*)(&Ws[kk][tx * 4]);
            a0.x = fmaf(xv.x, wv.x, a0.x); a0.y = fmaf(xv.x, wv.y, a0.y);
            a0.z = fmaf(xv.x, wv.z, a0.z); a0.w = fmaf(xv.x, wv.w, a0.w);
            a1.x = fmaf(xv.y, wv.x, a1.x); a1.y = fmaf(xv.y, wv.y, a1.y);
            a1.z = fmaf(xv.y, wv.z, a1.z); a1.w = fmaf(xv.y, wv.w, a1.w);
            a2.x = fmaf(xv.z, wv.x, a2.x); a2.y = fmaf(xv.z, wv.y, a2.y);
            a2.z = fmaf(xv.z, wv.z, a2.z); a2.w = fmaf(xv.z, wv.w, a2.w);
            a3.x = fmaf(xv.w, wv.x, a3.x); a3.y = fmaf(xv.w, wv.y, a3.y);
            a3.z = fmaf(xv.w, wv.z, a3.z); a3.w = fmaf(xv.w, wv.w, a3.w);
        }
        __syncthreads();
    }
    float* pb = P + (size_t)ks * SEQ * N;
    *(float4*)(pb + (size_t)(ty * 4 + 0) * N + jb + tx * 4) = a0;
    *(float4*)(pb + (size_t)(ty * 4 + 1) * N + jb + tx * 4) = a1;
    *(float4*)(pb + (size_t)(ty * 4 + 2) * N + jb + tx * 4) = a2;
    *(float4*)(pb + (size_t)(ty * 4 + 3) * N + jb + tx * 4) = a3;
}

__global__ __launch_bounds__(256) void reduce_ks(const float* __restrict__ P,
                                                 float* __restrict__ Y, int n4) {
    int t = blockIdx.x * 256 + threadIdx.x;
    if (t >= n4) return;
    const float4* p4 = (const float4*)P;
    float4 r = p4[t];
    #pragma unroll
    for (int i = 1; i < KS; ++i) {
        float4 v = p4[t + (size_t)i * n4];
        r.x += v.x; r.y += v.y; r.z += v.z; r.w += v.w;
    }
    ((float4*)Y)[t] = r;
}

// ---------------------------------------------------------------------------
// Scalar RoPE (unchanged, verified). sincosf(x, &sin, &cos) — sin FIRST.
// ---------------------------------------------------------------------------
__global__ __launch_bounds__(256) void rope_scalar(float* __restrict__ qkv,
                                                   const int* __restrict__ ia,
                                                   const int* __restrict__ ib) {
    int t = blockIdx.x * 256 + threadIdx.x;
    if (t >= SEQ * (NH + NKV) * 64) return;
    int i = t & 63;
    int h = (t >> 6) % (NH + NKV);
    int s = t / ((NH + NKV) * 64);
    int pos = max(ia[s], ib[s]) - 1;
    float* base = qkv + (size_t)s * QKV_N + (size_t)h * DH;
    float ang = (float)pos / powf(10000.0f, (float)i * 2.0f / (float)DH);
    float sn, c;
    sincosf(ang, &sn, &c);
    float x1 = base[i];
    float x2 = base[i + 64];
    base[i]      = x1 * c - x2 * sn;
    base[i + 64] = x2 * c + x1 * sn;
}

// ---------------------------------------------------------------------------
// Flash-decode attention v6: in-register QK^T during staging (K never in LDS).
// Block per (s, kv, split); 4 waves. Thread (sr=tid>>3, sq=tid&7) stages token
// row sr: 16 K dims + 16 V dims in registers; computes 4 head-dots in-reg;
// 8-lane shfl butterfly reduces; scores + V go to LDS (double-buffered).
// Softmax per wave (head) in registers; PV from LDS. One barrier per round.
// ---------------------------------------------------------------------------
__global__ __launch_bounds__(256) void attn_reg(const float* __restrict__ qkv,
                                                const float* __restrict__ k_cache,
                                                const float* __restrict__ v_cache,
                                                const int* __restrict__ ia,
                                                const int* __restrict__ ib,
                                                const int* __restrict__ block_tables,
                                                float* __restrict__ po,
                                                float* __restrict__ pm,
                                                float* __restrict__ pl) {
    __shared__ float Vlds[2][RT][132];    // 33.8 KB
    __shared__ float sc_lds[2][GQ][34];   // 1.1 KB
    __shared__ int   btl[NPAGES];         // 256 B

    int b  = blockIdx.x;
    int t  = b & 7;
    int kv = (b >> 3) & 7;
    int s  = b >> 6;
    int tid = threadIdx.x;
    int lane = tid & 63;
    int g = tid >> 6;

    int L   = max(ia[s], ib[s]);
    int pos = L - 1;
    int c_lo = t * TPS;
    if (c_lo >= L) return;              // inactive split (block-uniform)
    int c_hi = min(c_lo + TPS, L);
    int n = c_hi - c_lo;
    int nrounds = (n + RT - 1) >> 5;

    const int sr = tid >> 3;            // token row 0..31
    const int sq = tid & 7;             // dim slot 0..7

    if (tid < NPAGES) btl[tid] = block_tables[s * NPAGES + tid];
    __syncthreads();

    const float* knew = qkv + (size_t)s * QKV_N + (size_t)NH * DH + (size_t)kv * DH;
    const float* vnew = qkv + (size_t)s * QKV_N + (size_t)(NH + NKV) * DH + (size_t)kv * DH;

    // q fragments for all 4 heads: dims at float4-slots sq, sq+8, sq+16, sq+24.
    float4 qf[GQ][4];
    #pragma unroll
    for (int gg = 0; gg < GQ; ++gg) {
        const float4* qr = (const float4*)(qkv + (size_t)s * QKV_N
                                           + (size_t)(kv * GQ + gg) * DH);
        #pragma unroll
        for (int j = 0; j < 4; ++j) {
            float4 v = qr[sq + 8 * j];
            v.x *= SCALE; v.y *= SCALE; v.z *= SCALE; v.w *= SCALE;
            qf[gg][j] = v;
        }
    }

    float4 ka0, ka1, ka2, ka3, va0, va1, va2, va3;
    bool vrow;

#define LOADR(BASE) do {                                                        \
    int cc = c_lo + (BASE) + sr;                                                \
    vrow = cc < c_hi;                                                           \
    int cs = vrow ? cc : pos;                                                   \
    const float* kp_ = (cs == pos) ? knew                                       \
        : k_cache + ((size_t)btl[cs >> 4] * BS + (cs & 15)) * (size_t)(NKV * DH)\
                  + (size_t)kv * DH;                                            \
    const float* vp_ = (cs == pos) ? vnew                                       \
        : v_cache + ((size_t)btl[cs >> 4] * BS + (cs & 15)) * (size_t)(NKV * DH)\
                  + (size_t)kv * DH;                                            \
    const float4* kp4_ = (const float4*)kp_;                                    \
    const float4* vp4_ = (const float4*)vp_;                                    \
    ka0 = kp4_[sq];      ka1 = kp4_[sq + 8];                                    \
    ka2 = kp4_[sq + 16]; ka3 = kp4_[sq + 24];                                   \
    va0 = vp4_[sq];      va1 = vp4_[sq + 8];                                    \
    va2 = vp4_[sq + 16]; va3 = vp4_[sq + 24];                                   \
} while (0)

#define DOT4(Q, K) ((Q).x*(K).x + (Q).y*(K).y + (Q).z*(K).z + (Q).w*(K).w)

#define STORER(BUF) do {                                                        \
    float pp0 = DOT4(qf[0][0],ka0)+DOT4(qf[0][1],ka1)                           \
              + DOT4(qf[0][2],ka2)+DOT4(qf[0][3],ka3);                          \
    float pp1 = DOT4(qf[1][0],ka0)+DOT4(qf[1][1],ka1)                           \
              + DOT4(qf[1][2],ka2)+DOT4(qf[1][3],ka3);                          \
    float pp2 = DOT4(qf[2][0],ka0)+DOT4(qf[2][1],ka1)                           \
              + DOT4(qf[2][2],ka2)+DOT4(qf[2][3],ka3);                          \
    float pp3 = DOT4(qf[3][0],ka0)+DOT4(qf[3][1],ka1)                           \
              + DOT4(qf[3][2],ka2)+DOT4(qf[3][3],ka3);                          \
    pp0 += __shfl_xor(pp0, 1, 64); pp0 += __shfl_xor(pp0, 2, 64);               \
    pp0 += __shfl_xor(pp0, 4, 64);                                              \
    pp1 += __shfl_xor(pp1, 1, 64); pp1 += __shfl_xor(pp1, 2, 64);               \
    pp1 += __shfl_xor(pp1, 4, 64);                                              \
    pp2 += __shfl_xor(pp2, 1, 64); pp2 += __shfl_xor(pp2, 2, 64);               \
    pp2 += __shfl_xor(pp2, 4, 64);                                              \
    pp3 += __shfl_xor(pp3, 1, 64); pp3 += __shfl_xor(pp3, 2, 64);               \
    pp3 += __shfl_xor(pp3, 4, 64);                                              \
    if (sq < 4) {                                                               \
        float ppsel = (sq == 0) ? pp0 : (sq == 1) ? pp1 : (sq == 2) ? pp2 : pp3;\
        sc_lds[BUF][sq][sr] = vrow ? ppsel : -1e30f;                            \
    }                                                                           \
    *(float4*)(&Vlds[BUF][sr][4 * sq])        = va0;                            \
    *(float4*)(&Vlds[BUF][sr][4 * (sq + 8)])  = va1;                            \
    *(float4*)(&Vlds[BUF][sr][4 * (sq + 16)]) = va2;                            \
    *(float4*)(&Vlds[BUF][sr][4 * (sq + 24)]) = va3;                            \
} while (0)

    // prologue: stage round 0
    LOADR(0);
    STORER(0);
    __syncthreads();

    float m = -1e30f, l = 0.f, o0 = 0.f, o1 = 0.f;
    int cur = 0;
    const int tkn = lane & 31;

    for (int r = 0; r < nrounds; ++r) {
        int base = r << 5;
        if (r + 1 < nrounds) LOADR(base + RT);   // issue next-round global loads

        // softmax (online) for this round, per wave g
        float sco = sc_lds[cur][g][tkn];
        float rm = sco;
        #pragma unroll
        for (int off = 16; off; off >>= 1) rm = fmaxf(rm, __shfl_xor(rm, off, 64));
        float m_new = fmaxf(m, rm);
        float p = expf(sco - m_new);             // -1e30 rows -> 0
        float ps = p;
        #pragma unroll
        for (int off = 16; off; off >>= 1) ps += __shfl_xor(ps, off, 64);
        float rescale = expf(m - m_new);
        l = l * rescale + ps;
        o0 *= rescale; o1 *= rescale;
        m = m_new;

        // PV from LDS; p broadcast from lane j
        int cnt = min(RT, n - base);
        for (int j = 0; j < cnt; ++j) {
            float pj = __shfl(p, j, 64);
            float2 v = *(const float2*)(&Vlds[cur][j][2 * lane]);
            o0 = fmaf(pj, v.x, o0);
            o1 = fmaf(pj, v.y, o1);
        }

        if (r + 1 < nrounds) {
            STORER(cur ^ 1);                     // scores in-reg + V to LDS
            __syncthreads();
            cur ^= 1;
        }
    }

    int idx = t * NHQ + s * NH + kv * GQ + g;
    float* ob = po + (size_t)idx * DH;
    ((float2*)ob)[lane] = make_float2(o0, o1);
    if (lane == 0) {
        pm[idx] = m;
        pl[idx] = l;
    }
#undef LOADR
#undef DOT4
#undef STORER
}

// ---------------------------------------------------------------------------
// Combine: block per (s,qh); active split count derived from L.
// ---------------------------------------------------------------------------
__global__ __launch_bounds__(128) void attn_combine(const float* __restrict__ po,
                                                    const float* __restrict__ pm,
                                                    const float* __restrict__ pl,
                                                    const int* __restrict__ ia,
                                                    const int* __restrict__ ib,
                                                    float* __restrict__ attn_out) {
    int sh = blockIdx.x;
    int s  = sh >> 5;
    int d  = threadIdx.x;
    int L  = max(ia[s], ib[s]);
    int nact = (L + TPS - 1) / TPS;
    float mv[CSPLIT];
    float M = -1e30f;
    for (int i = 0; i < nact; ++i) {
        mv[i] = pm[i * NHQ + sh];
        M = fmaxf(M, mv[i]);
    }
    float num = 0.f, denom = 0.f;
    for (int i = 0; i < nact; ++i) {
        float w = expf(mv[i] - M);
        denom += pl[i * NHQ + sh] * w;
        num   += po[(size_t)(i * NHQ + sh) * DH + d] * w;
    }
    attn_out[(size_t)sh * DH + d] = num / denom;
}

// ---------------------------------------------------------------------------
extern "C" void kernel_launch(void* const* d_in, const int* in_sizes, int n_in,
                              void* d_out, int out_size, void* d_ws, size_t ws_size,
                              hipStream_t stream) {
    const float *hidden = nullptr, *k_cache = nullptr, *v_cache = nullptr;
    const float *qkv_w = nullptr, *o_w = nullptr;
    const int *i64a = nullptr, *i64b = nullptr, *block_tables = nullptr;
    for (int i = 0; i < n_in; ++i) {
        switch (in_sizes[i]) {
            case SEQ * HID:          hidden = (const float*)d_in[i]; break;
            case 4096 * BS * NKV * DH:
                if (!k_cache) k_cache = (const float*)d_in[i];
                else          v_cache = (const float*)d_in[i];
                break;
            case QKV_N * HID:        qkv_w = (const float*)d_in[i]; break;
            case HID * HID:          o_w   = (const float*)d_in[i]; break;
            case SEQ * NPAGES:       block_tables = (const int*)d_in[i]; break;
            case SEQ:
                if (!i64a) i64a = (const int*)d_in[i];
                else       i64b = (const int*)d_in[i];
                break;
        }
    }
    float* out = (float*)d_out;

    static float* qkv_p  = nullptr;
    static float* attn_p = nullptr;
    static float* part_p = nullptr;
    static float* po_p   = nullptr;
    static float* pm_p   = nullptr;
    static float* pl_p   = nullptr;
    if (!qkv_p) {
        void* p;
        hipGetSymbolAddress(&p, HIP_SYMBOL(g_qkv));  qkv_p  = (float*)p;
        hipGetSymbolAddress(&p, HIP_SYMBOL(g_attn)); attn_p = (float*)p;
        hipGetSymbolAddress(&p, HIP_SYMBOL(g_part)); part_p = (float*)p;
        hipGetSymbolAddress(&p, HIP_SYMBOL(g_po));   po_p   = (float*)p;
        hipGetSymbolAddress(&p, HIP_SYMBOL(g_pm));   pm_p   = (float*)p;
        hipGetSymbolAddress(&p, HIP_SYMBOL(g_pl));   pl_p   = (float*)p;
    }

    // 1) QKV projection
    gemm_tile<<<dim3(QKV_N / 64, KS), 256, 0, stream>>>(hidden, qkv_w, part_p,
                                                        QKV_N, HID);
    reduce_ks<<<(SEQ * QKV_N / 4 + 255) / 256, 256, 0, stream>>>(part_p, qkv_p,
                                                                 SEQ * QKV_N / 4);
    // 2) RoPE
    rope_scalar<<<(SEQ * (NH + NKV) * 64) / 256, 256, 0, stream>>>(qkv_p, i64a, i64b);
    // 3) Flash-decode attention (in-register QK^T)
    attn_reg<<<SEQ * NKV * CSPLIT, 256, 0, stream>>>(qkv_p, k_cache, v_cache,
                                                     i64a, i64b, block_tables,
                                                     po_p, pm_p, pl_p);
    attn_combine<<<NHQ, 128, 0, stream>>>(po_p, pm_p, pl_p, i64a, i64b, attn_p);
    // 4) Output projection
    gemm_tile<<<dim3(HID / 64, KS), 256, 0, stream>>>(attn_p, o_w, part_p,
                                                      HID, HID);
    reduce_ks<<<(SEQ * HID / 4 + 255) / 256, 256, 0, stream>>>(part_p, out,
                                                               SEQ * HID / 4);
}